// Round 3
// baseline (213.734 us; speedup 1.0000x reference)
//
#include <hip/hip_runtime.h>
#include <hip/hip_bf16.h>
#include <math.h>

#define NB 2
#define NN 4096
#define FIN 128
#define FOUT 64
#define LALPHA 0.2f

// ws float-offsets
#define WS_S1  0                          // NB*NN
#define WS_S2  (NB*NN)                    // NB*NN
#define WS_L   (2*NB*NN)                  // NB*NN   (atomic accum, zeroed in k1)
#define WS_ACC (3*NB*NN)                  // NB*NN*FOUT (atomic accum, zeroed in k1)
#define WS_WHT (3*NB*NN + NB*NN*FOUT)     // NB*FOUT*NN ushorts (bf16 Wh^T, [b][f][j])

typedef __attribute__((ext_vector_type(8))) short short8;
typedef __attribute__((ext_vector_type(4))) float f32x4;

static __device__ inline unsigned int pack2bf(float x, float y) {
    float2 f2; f2.x = x; f2.y = y;
    __hip_bfloat162 pp = __float22bfloat162_rn(f2);
    return *reinterpret_cast<unsigned int*>(&pp);
}

// K1: Wh = h@W ; s1 = Wh@a1 ; s2 = Wh@a2 ; WhT bf16 [b][f][j] ; zero l/acc.
// One wave per (b,row); lane = out feature. Block = 4 waves = 4 consecutive rows.
__global__ __launch_bounds__(256) void k1_proj(const float* __restrict__ h,
                                               const float* __restrict__ W,
                                               const float* __restrict__ a,
                                               float* __restrict__ ws) {
    __shared__ float tbuf[4][68];
    int gid  = blockIdx.x * 256 + threadIdx.x;
    int wid  = gid >> 6;            // 0 .. NB*NN-1
    int lane = threadIdx.x & 63;
    int w    = threadIdx.x >> 6;
    const float* hrow = h + (size_t)wid * FIN;
    float h0 = hrow[lane];
    float h1 = hrow[64 + lane];
    float acc = 0.f;
#pragma unroll
    for (int f = 0; f < 64; ++f) {
        float hf = __shfl(h0, f);
        acc = fmaf(hf, W[f * FOUT + lane], acc);
    }
#pragma unroll
    for (int f = 0; f < 64; ++f) {
        float hf = __shfl(h1, f);
        acc = fmaf(hf, W[(64 + f) * FOUT + lane], acc);
    }
    tbuf[w][lane] = acc;
    float v1 = acc * a[lane];
    float v2 = acc * a[FOUT + lane];
#pragma unroll
    for (int off = 32; off; off >>= 1) {
        v1 += __shfl_xor(v1, off);
        v2 += __shfl_xor(v2, off);
    }
    if (lane == 0) {
        ws[WS_S1 + wid] = v1;
        ws[WS_S2 + wid] = v2;
        ws[WS_L + wid]  = 0.f;
    }
    ws[WS_ACC + (size_t)wid * FOUT + lane] = 0.f;   // zero accumulator row
    __syncthreads();
    // transpose 4 rows x 64 f -> WhT bf16 [b][f][n0..n0+3]
    if (threadIdx.x < 64) {
        int f = threadIdx.x;
        int wid0 = blockIdx.x * 4;
        int b  = wid0 >> 12;         // wid0 / NN
        int n0 = wid0 & (NN - 1);
        unsigned short* whT = (unsigned short*)(ws + WS_WHT);
        uint2 pk;
        pk.x = pack2bf(tbuf[0][f], tbuf[1][f]);
        pk.y = pack2bf(tbuf[2][f], tbuf[3][f]);
        *(uint2*)&whT[(size_t)(b * FOUT + f) * NN + n0] = pk;
    }
}

// K3: fused masked softmax + P@Wh via MFMA, zero LDS.
// Wave = 32 rows (two 16-row m-tiles) x 128 j. A-fragments are built directly
// in registers: lane (col=lane&15, quad=lane>>4) computes the 8 scores for
// row i0+[tile*16]+col, j = jb + ks*32 + quad*8 .. +8 -- exactly the MFMA
// A-operand layout. No LDS, no barriers. Partials merged by atomicAdd.
// grid = 128 i-tiles x 8 j-segments = 1024 blocks x 256 threads.
__global__ __launch_bounds__(256, 4) void k3_attn(const int* __restrict__ adj,
                                                  float* __restrict__ ws) {
    const int tid  = threadIdx.x;
    const int w    = tid >> 6;
    const int lane = tid & 63;
    const int col  = lane & 15;
    const int quad = lane >> 4;
    const int itile = blockIdx.x >> 3;
    const int seg   = blockIdx.x & 7;
    const int i0    = itile * 32;
    const int jb    = seg * 512 + w * 128;   // wave's 128-j range

    const float* __restrict__ s1 = ws + WS_S1;
    const float* __restrict__ s2 = ws + WS_S2;
    const unsigned short* __restrict__ whT = (const unsigned short*)(ws + WS_WHT);

    float s1a[2][2];   // [tile][batch]
#pragma unroll
    for (int t = 0; t < 2; ++t)
#pragma unroll
        for (int b = 0; b < 2; ++b) s1a[t][b] = s1[b * NN + i0 + t * 16 + col];

    f32x4 acc[2][2][4];     // [tile][batch][nt]
    float lsum[2][2];       // [tile][batch]
#pragma unroll
    for (int t = 0; t < 2; ++t)
#pragma unroll
        for (int b = 0; b < 2; ++b) {
#pragma unroll
            for (int nt = 0; nt < 4; ++nt) acc[t][b][nt] = (f32x4)0.f;
            lsum[t][b] = 0.f;
        }

#pragma unroll
    for (int ks = 0; ks < 4; ++ks) {
        const int j8 = jb + ks * 32 + quad * 8;   // this lane's 8-j base
        // adj for both m-tiles (shared across batches): 8 ints each
        int4 av0a = *(const int4*)&adj[(size_t)(i0 + col) * NN + j8];
        int4 av0b = *(const int4*)&adj[(size_t)(i0 + col) * NN + j8 + 4];
        int4 av1a = *(const int4*)&adj[(size_t)(i0 + 16 + col) * NN + j8];
        int4 av1b = *(const int4*)&adj[(size_t)(i0 + 16 + col) * NN + j8 + 4];
#pragma unroll
        for (int b = 0; b < 2; ++b) {
            float4 s2lo = *(const float4*)&s2[b * NN + j8];
            float4 s2hi = *(const float4*)&s2[b * NN + j8 + 4];
            float sj[8] = {s2lo.x, s2lo.y, s2lo.z, s2lo.w,
                           s2hi.x, s2hi.y, s2hi.z, s2hi.w};
            int am[2][8] = {{av0a.x, av0a.y, av0a.z, av0a.w,
                             av0b.x, av0b.y, av0b.z, av0b.w},
                            {av1a.x, av1a.y, av1a.z, av1a.w,
                             av1b.x, av1b.y, av1b.z, av1b.w}};
            short8 afrag[2];
#pragma unroll
            for (int t = 0; t < 2; ++t) {
                float p[8];
#pragma unroll
                for (int jj = 0; jj < 8; ++jj) {
                    float e = s1a[t][b] + sj[jj];
                    e = fmaxf(e, LALPHA * e);          // leakyrelu
                    float pe = __expf(e);
                    p[jj] = am[t][jj] > 0 ? pe : 0.f;  // mask
                    lsum[t][b] += p[jj];
                }
                unsigned int pk[4];
#pragma unroll
                for (int q = 0; q < 4; ++q) pk[q] = pack2bf(p[2 * q], p[2 * q + 1]);
                afrag[t] = *(short8*)pk;
            }
            // B fragments shared by both m-tiles
#pragma unroll
            for (int nt = 0; nt < 4; ++nt) {
                short8 bfrag = *(const short8*)
                    &whT[(size_t)(b * FOUT + nt * 16 + col) * NN + j8];
                acc[0][b][nt] = __builtin_amdgcn_mfma_f32_16x16x32_bf16(
                    afrag[0], bfrag, acc[0][b][nt], 0, 0, 0);
                acc[1][b][nt] = __builtin_amdgcn_mfma_f32_16x16x32_bf16(
                    afrag[1], bfrag, acc[1][b][nt], 0, 0, 0);
            }
        }
    }

    // ---- epilogue. D layout: col=lane&15, row=quad*4+reg ----
    float* lacc = ws + WS_L;
    float* aacc = ws + WS_ACC;
#pragma unroll
    for (int t = 0; t < 2; ++t)
#pragma unroll
        for (int b = 0; b < 2; ++b) {
            float v = lsum[t][b];
            v += __shfl_xor(v, 16);
            v += __shfl_xor(v, 32);
            if (quad == 0) atomicAdd(&lacc[b * NN + i0 + t * 16 + col], v);
#pragma unroll
            for (int nt = 0; nt < 4; ++nt)
#pragma unroll
                for (int reg = 0; reg < 4; ++reg) {
                    int row = i0 + t * 16 + quad * 4 + reg;
                    atomicAdd(&aacc[(size_t)(b * NN + row) * FOUT + nt * 16 + col],
                              acc[t][b][nt][reg]);
                }
        }
}

// K4: out = elu(acc / l)
__global__ __launch_bounds__(256) void k4_fin(const float* __restrict__ ws,
                                              float* __restrict__ out) {
    int idx = blockIdx.x * 256 + threadIdx.x;    // 0 .. NB*NN*FOUT-1
    int row = idx >> 6;
    float l = ws[WS_L + row];
    float v = ws[WS_ACC + idx] / l;
    out[idx] = v > 0.f ? v : (__expf(v) - 1.f);
}

extern "C" void kernel_launch(void* const* d_in, const int* in_sizes, int n_in,
                              void* d_out, int out_size, void* d_ws, size_t ws_size,
                              hipStream_t stream) {
    const float* h   = (const float*)d_in[0];
    const int*   adj = (const int*)d_in[1];
    const float* W   = (const float*)d_in[2];
    const float* a   = (const float*)d_in[3];
    float* ws  = (float*)d_ws;
    float* out = (float*)d_out;

    hipLaunchKernelGGL(k1_proj, dim3(NB * NN / 4), dim3(256), 0, stream, h, W, a, ws);
    hipLaunchKernelGGL(k3_attn, dim3(128 * 8),     dim3(256), 0, stream, adj, ws);
    hipLaunchKernelGGL(k4_fin,  dim3(NB * NN * FOUT / 256), dim3(256), 0, stream, ws, out);
}

// Round 4
// 161.781 us; speedup vs baseline: 1.3211x; 1.3211x over previous
//
#include <hip/hip_runtime.h>
#include <hip/hip_bf16.h>
#include <math.h>

#define NB 2
#define NN 4096
#define FIN 128
#define FOUT 64
#define LALPHA 0.2f
#define NJC 16            // j-chunks per row (chunk = 256 j)

// ws float-offsets
#define WS_S1   0                          // NB*NN
#define WS_S2   (NB*NN)                    // NB*NN
#define WS_WHT  (2*NB*NN)                  // NB*FOUT*NN ushorts = NB*FOUT*NN/2 floats
#define WS_LSL  (2*NB*NN + NB*FOUT*NN/2)   // 256 rt * NJC * 32 floats (l partials)
#define WS_SLAB (WS_LSL + 256*NJC*32)      // 256 rt * NJC * 2048 floats (acc partials)

typedef __attribute__((ext_vector_type(8))) short short8;
typedef __attribute__((ext_vector_type(4))) float f32x4;

static __device__ inline unsigned int pack2bf(float x, float y) {
    float2 f2; f2.x = x; f2.y = y;
    __hip_bfloat162 pp = __float22bfloat162_rn(f2);
    return *reinterpret_cast<unsigned int*>(&pp);
}

// K1: Wh = h@W ; s1 = Wh@a1 ; s2 = Wh@a2 ; WhT bf16 [b][f][j].
// One wave per (b,row); lane = out feature. Block = 4 waves = 4 consecutive rows.
__global__ __launch_bounds__(256) void k1_proj(const float* __restrict__ h,
                                               const float* __restrict__ W,
                                               const float* __restrict__ a,
                                               float* __restrict__ ws) {
    __shared__ float tbuf[4][68];
    int gid  = blockIdx.x * 256 + threadIdx.x;
    int wid  = gid >> 6;            // 0 .. NB*NN-1
    int lane = threadIdx.x & 63;
    int w    = threadIdx.x >> 6;
    const float* hrow = h + (size_t)wid * FIN;
    float h0 = hrow[lane];
    float h1 = hrow[64 + lane];
    float acc = 0.f;
#pragma unroll
    for (int f = 0; f < 64; ++f) {
        float hf = __shfl(h0, f);
        acc = fmaf(hf, W[f * FOUT + lane], acc);
    }
#pragma unroll
    for (int f = 0; f < 64; ++f) {
        float hf = __shfl(h1, f);
        acc = fmaf(hf, W[(64 + f) * FOUT + lane], acc);
    }
    tbuf[w][lane] = acc;
    float v1 = acc * a[lane];
    float v2 = acc * a[FOUT + lane];
#pragma unroll
    for (int off = 32; off; off >>= 1) {
        v1 += __shfl_xor(v1, off);
        v2 += __shfl_xor(v2, off);
    }
    if (lane == 0) {
        ws[WS_S1 + wid] = v1;
        ws[WS_S2 + wid] = v2;
    }
    __syncthreads();
    // transpose 4 rows x 64 f -> WhT bf16 [b][f][n0..n0+3]
    if (threadIdx.x < 64) {
        int f = threadIdx.x;
        int wid0 = blockIdx.x * 4;
        int b  = wid0 >> 12;         // wid0 / NN
        int n0 = wid0 & (NN - 1);
        unsigned short* whT = (unsigned short*)(ws + WS_WHT);
        uint2 pk;
        pk.x = pack2bf(tbuf[0][f], tbuf[1][f]);
        pk.y = pack2bf(tbuf[2][f], tbuf[3][f]);
        *(uint2*)&whT[(size_t)(b * FOUT + f) * NN + n0] = pk;
    }
}

// K3: fused masked softmax + P@Wh via MFMA. Zero LDS, zero atomics.
// Wave = 16 rows x 256 j. A-fragment built in registers (lane col=lane&15 owns
// row i0+col, quad=lane>>4 owns j-subrange). Partial D-tile + l written as
// plain coalesced stores to a per-(rowtile,jchunk) slab; k4 reduces.
// grid = 256 row-tiles x NJC(16) j-chunks / 4 waves = 1024 blocks.
__global__ __launch_bounds__(256, 4) void k3_attn(const int* __restrict__ adj,
                                                  float* __restrict__ ws) {
    const int tid  = threadIdx.x;
    const int w    = tid >> 6;
    const int lane = tid & 63;
    const int col  = lane & 15;
    const int quad = lane >> 4;
    const int rt   = blockIdx.x >> 2;            // row-tile 0..255
    const int jc   = (blockIdx.x & 3) * 4 + w;   // j-chunk 0..15
    const int i0   = rt * 16;
    const int jbase = jc * 256;

    const float* __restrict__ s1 = ws + WS_S1;
    const float* __restrict__ s2 = ws + WS_S2;
    const unsigned short* __restrict__ whT = (const unsigned short*)(ws + WS_WHT);

    float s1a[2];
#pragma unroll
    for (int b = 0; b < 2; ++b) s1a[b] = s1[b * NN + i0 + col];

    f32x4 acc[2][4];        // [batch][nt]
    float lsum[2] = {0.f, 0.f};
#pragma unroll
    for (int b = 0; b < 2; ++b)
#pragma unroll
        for (int nt = 0; nt < 4; ++nt) acc[b][nt] = (f32x4)0.f;

#pragma unroll
    for (int ks = 0; ks < 8; ++ks) {
        const int j8 = jbase + ks * 32 + quad * 8;   // this lane's 8-j base
        int4 ava = *(const int4*)&adj[(size_t)(i0 + col) * NN + j8];
        int4 avb = *(const int4*)&adj[(size_t)(i0 + col) * NN + j8 + 4];
        int am[8] = {ava.x, ava.y, ava.z, ava.w, avb.x, avb.y, avb.z, avb.w};
#pragma unroll
        for (int b = 0; b < 2; ++b) {
            float4 s2lo = *(const float4*)&s2[b * NN + j8];
            float4 s2hi = *(const float4*)&s2[b * NN + j8 + 4];
            float sj[8] = {s2lo.x, s2lo.y, s2lo.z, s2lo.w,
                           s2hi.x, s2hi.y, s2hi.z, s2hi.w};
            float p[8];
#pragma unroll
            for (int jj = 0; jj < 8; ++jj) {
                float e = s1a[b] + sj[jj];
                e = fmaxf(e, LALPHA * e);          // leakyrelu
                float pe = __expf(e);
                p[jj] = am[jj] > 0 ? pe : 0.f;     // mask
                lsum[b] += p[jj];
            }
            unsigned int pk[4];
#pragma unroll
            for (int q = 0; q < 4; ++q) pk[q] = pack2bf(p[2 * q], p[2 * q + 1]);
            short8 afrag = *(short8*)pk;
#pragma unroll
            for (int nt = 0; nt < 4; ++nt) {
                short8 bfrag = *(const short8*)
                    &whT[(size_t)(b * FOUT + nt * 16 + col) * NN + j8];
                acc[b][nt] = __builtin_amdgcn_mfma_f32_16x16x32_bf16(
                    afrag, bfrag, acc[b][nt], 0, 0, 0);
            }
        }
    }

    // ---- epilogue: plain coalesced stores of partials ----
    float* slab = ws + WS_SLAB + (size_t)(rt * NJC + jc) * 2048;
    float* lsl  = ws + WS_LSL  + (size_t)(rt * NJC + jc) * 32;
#pragma unroll
    for (int b = 0; b < 2; ++b) {
        // l: sum over quads -> row (=col) total for this j-chunk
        float v = lsum[b];
        v += __shfl_xor(v, 16);
        v += __shfl_xor(v, 32);
        if (quad == 0) lsl[b * 16 + col] = v;
#pragma unroll
        for (int nt = 0; nt < 4; ++nt)
#pragma unroll
            for (int reg = 0; reg < 4; ++reg)
                slab[(((b * 4 + nt) * 4 + reg) << 6) + lane] = acc[b][nt][reg];
    }
}

// K4: reduce NJC partials, out = elu(acc / l). One thread per output element.
__global__ __launch_bounds__(256) void k4_fin(const float* __restrict__ ws,
                                              float* __restrict__ out) {
    int idx = blockIdx.x * 256 + threadIdx.x;    // (b, row, f) flat
    int f   = idx & 63;
    int row = (idx >> 6) & (NN - 1);
    int b   = idx >> 18;
    int rt  = row >> 4;
    int r16 = row & 15;
    int quad = r16 >> 2, reg = r16 & 3;
    int col  = f & 15,  nt  = f >> 4;
    int lane = quad * 16 + col;
    const float* slab = ws + WS_SLAB + (size_t)rt * NJC * 2048
                        + (((b * 4 + nt) * 4 + reg) << 6) + lane;
    const float* lsl  = ws + WS_LSL + (size_t)rt * NJC * 32 + b * 16 + r16;
    float a = 0.f, l = 0.f;
#pragma unroll
    for (int jc = 0; jc < NJC; ++jc) {
        a += slab[jc * 2048];
        l += lsl[jc * 32];
    }
    float v = a / l;
    out[idx] = v > 0.f ? v : (__expf(v) - 1.f);
}

extern "C" void kernel_launch(void* const* d_in, const int* in_sizes, int n_in,
                              void* d_out, int out_size, void* d_ws, size_t ws_size,
                              hipStream_t stream) {
    const float* h   = (const float*)d_in[0];
    const int*   adj = (const int*)d_in[1];
    const float* W   = (const float*)d_in[2];
    const float* a   = (const float*)d_in[3];
    float* ws  = (float*)d_ws;
    float* out = (float*)d_out;

    hipLaunchKernelGGL(k1_proj, dim3(NB * NN / 4), dim3(256), 0, stream, h, W, a, ws);
    hipLaunchKernelGGL(k3_attn, dim3(256 * NJC / 4), dim3(256), 0, stream, adj, ws);
    hipLaunchKernelGGL(k4_fin,  dim3(NB * NN * FOUT / 256), dim3(256), 0, stream, ws, out);
}